// Round 2
// 1423.630 us; speedup vs baseline: 1.8911x; 1.8911x over previous
//
#include <hip/hip_runtime.h>

// ---------------- problem constants ----------------
#define DIM    384
#define HEADS  12
#define NPIX   3136      // 56*56
#define BATCH  32
#define AGENTS 49
#define HD     32

typedef unsigned short u16;
typedef unsigned int   u32;
typedef __attribute__((ext_vector_type(8))) short short8;   // 8 bf16 (4 VGPRs)
typedef __attribute__((ext_vector_type(4))) float f32x4;

__device__ __forceinline__ float bf2f(u16 u) { return __uint_as_float(((u32)u) << 16); }
__device__ __forceinline__ u16 f2bf(float f) {
    u32 i = __float_as_uint(f);
    u32 r = i + 0x7fffu + ((i >> 16) & 1u);   // round-to-nearest-even
    return (u16)(r >> 16);
}

// unpack 32 contiguous bf16 -> 32 floats (16B-aligned source)
__device__ __forceinline__ void unpack_row32(const u16* p, float* f) {
    const uint4* q = (const uint4*)p;
#pragma unroll
    for (int i = 0; i < 4; i++) {
        uint4 u = q[i];
        u32 w0 = u.x, w1 = u.y, w2 = u.z, w3 = u.w;
        f[i*8+0] = __uint_as_float(w0 << 16); f[i*8+1] = __uint_as_float(w0 & 0xffff0000u);
        f[i*8+2] = __uint_as_float(w1 << 16); f[i*8+3] = __uint_as_float(w1 & 0xffff0000u);
        f[i*8+4] = __uint_as_float(w2 << 16); f[i*8+5] = __uint_as_float(w2 & 0xffff0000u);
        f[i*8+6] = __uint_as_float(w3 << 16); f[i*8+7] = __uint_as_float(w3 & 0xffff0000u);
    }
}

// generic: src fp32 [R][C] -> dst bf16 [C][R]  (R, C multiples of 64)
__global__ __launch_bounds__(256) void transpose_mat(const float* __restrict__ src, u16* __restrict__ dst,
                                                     int R, int C) {
    __shared__ u16 tile[64][65];
    int c0 = blockIdx.x * 64, r0 = blockIdx.y * 64;
    int t0 = threadIdx.x & 63, t1 = threadIdx.x >> 6;
#pragma unroll
    for (int i = 0; i < 16; i++) {
        int r = t1 + i*4;
        tile[t0][r] = f2bf(src[(size_t)(r0 + r)*C + c0 + t0]);
    }
    __syncthreads();
#pragma unroll
    for (int i = 0; i < 16; i++) {
        int c = t1 + i*4;
        dst[(size_t)(c0 + c)*R + r0 + t0] = tile[c][t0];
    }
}

// ---------------- bilinear bias upsample 7x7 -> 56x56 (fp32 -> fp32) ----------------
__global__ __launch_bounds__(256) void upsample_bias(const float* __restrict__ src, float* __restrict__ dst) {
    int idx = blockIdx.x * 256 + threadIdx.x;          // < 12*49*3136
    int xo = idx % 56; int t = idx / 56;
    int yo = t % 56;   int ha = t / 56;                // h*49 + a
    float fy = yo * 0.125f - 0.4375f;
    float fx = xo * 0.125f - 0.4375f;
    float y0f = floorf(fy), x0f = floorf(fx);
    float wy = fy - y0f, wx = fx - x0f;
    int y0 = (int)y0f, x0 = (int)x0f;
    int y0c = max(y0, 0), y1c = min(y0 + 1, 6);
    int x0c = max(x0, 0), x1c = min(x0 + 1, 6);
    const float* sp = src + (size_t)ha * 49;
    float v00 = sp[y0c*7 + x0c], v01 = sp[y0c*7 + x1c];
    float v10 = sp[y1c*7 + x0c], v11 = sp[y1c*7 + x1c];
    dst[idx] = (1.f-wy)*((1.f-wx)*v00 + wx*v01) + wy*((1.f-wx)*v10 + wx*v11);
}

// ---------------- zero-init for stage1 partial accumulators (replaces hipMemsetAsync) ----------------
__global__ __launch_bounds__(256) void zero_init(float* __restrict__ p, int n) {
    int i = blockIdx.x * 256 + threadIdx.x;
    if (i < n) p[i] = 0.f;
}

// ---------------- shared MFMA fragment compute (tiles staged in As/Bs, XOR swizzle) ----------------
__device__ __forceinline__ void mfma_tile(const short* As, const short* Bs, f32x4 acc[4][4],
                                          int wm, int wn, int quad, int lr) {
#pragma unroll
    for (int ks = 0; ks < 2; ks++) {
        int g = ks*4 + quad;
        short8 af[4], bg[4];
#pragma unroll
        for (int im = 0; im < 4; im++) {
            int r = wm*64 + im*16 + lr;
            af[im] = *(const short8*)&As[r*64 + ((g ^ (r & 7)) << 3)];
        }
#pragma unroll
        for (int in_ = 0; in_ < 4; in_++) {
            int r = wn*64 + in_*16 + lr;
            bg[in_] = *(const short8*)&Bs[r*64 + ((g ^ (r & 7)) << 3)];
        }
#pragma unroll
        for (int im = 0; im < 4; im++)
#pragma unroll
            for (int in_ = 0; in_ < 4; in_++)
                acc[im][in_] = __builtin_amdgcn_mfma_f32_16x16x32_bf16(af[im], bg[in_], acc[im][in_], 0, 0, 0);
    }
}

// QKV GEMM, reading x (fp32, [b][384][3136]) with in-staging transpose + bf16 convert.
__global__ __launch_bounds__(256) void gemm_qkv(const float* __restrict__ x, const u16* __restrict__ Bw,
                                                const float* __restrict__ bias,
                                                u16* __restrict__ qb, u16* __restrict__ kb, u16* __restrict__ vb) {
    __shared__ __align__(16) short As[128*64];
    __shared__ __align__(16) short Bs[128*64];
    f32x4 acc[4][4] = {};
    const int n0 = blockIdx.x * 128;
    const int p0 = blockIdx.y * 128;
    const int bb = blockIdx.z;
    const int tid  = threadIdx.x;
    const int lane = tid & 63, wave = tid >> 6;
    const int wm = wave >> 1, wn = wave & 1;
    const int quad = lane >> 4, lr = lane & 15;
    const int ch_ = tid >> 2;            // 0..63  (channel within K-tile)
    const int seg = tid & 3;             // 0..3   (32-pixel segment)
    const int pbase = seg * 32;
    const bool segok = (p0 + pbase) < NPIX;   // NPIX % 32 == 0: segment fully valid or fully OOB

    for (int kt = 0; kt < DIM; kt += 64) {
        __syncthreads();
        // --- stage A: load 32 fp32 pixels of one channel, convert, transpose into LDS ---
        u16 vals[32];
        if (segok) {
            const float4* xp = (const float4*)(x + ((size_t)bb*DIM + kt + ch_)*NPIX + p0 + pbase);
#pragma unroll
            for (int j = 0; j < 8; j++) {
                float4 u = xp[j];
                vals[j*4+0] = f2bf(u.x); vals[j*4+1] = f2bf(u.y);
                vals[j*4+2] = f2bf(u.z); vals[j*4+3] = f2bf(u.w);
            }
        } else {
#pragma unroll
            for (int i = 0; i < 32; i++) vals[i] = 0;
        }
#pragma unroll
        for (int i = 0; i < 32; i++) {
            int r = pbase + i;           // pbase % 8 == 0 -> (r&7) == (i&7)
            As[r*64 + (((ch_ >> 3) ^ (i & 7)) << 3) + (ch_ & 7)] = (short)vals[i];
        }
        // --- stage B: qkvwT rows (k-contiguous bf16) ---
#pragma unroll
        for (int c2 = 0; c2 < 4; c2++) {
            int idx = c2*256 + tid;
            int r = idx >> 3, g = idx & 7;
            int so = r*64 + ((g ^ (r & 7)) << 3);
            *(uint4*)&Bs[so] = *(const uint4*)&Bw[(size_t)(n0 + r)*DIM + kt + g*8];
        }
        __syncthreads();
        mfma_tile(As, Bs, acc, wm, wn, quad, lr);
    }
    // --- epilogue: scatter into per-head q/k/v (bf16) ---
#pragma unroll
    for (int in_ = 0; in_ < 4; in_++) {
        int col = n0 + wn*64 + in_*16 + lr;           // < 1152
        int which = col / 384;
        int ch = col - which*384;
        int head = ch >> 5, d = ch & 31;
        float bcol = bias[col];
        u16* dstp = (which == 0) ? qb : ((which == 1) ? kb : vb);
#pragma unroll
        for (int im = 0; im < 4; im++) {
            int prow = p0 + wm*64 + im*16 + quad*4;
#pragma unroll
            for (int r = 0; r < 4; r++) {
                int pix = prow + r;
                if (pix < NPIX) {
                    float v = acc[im][in_][r] + bcol;
                    dstp[((size_t)(bb*HEADS + head)*NPIX + pix)*HD + d] = f2bf(v);
                }
            }
        }
    }
}

// proj GEMM: obuf(bf16)[100352][384] @ projwT(bf16)[384][384]^T + bias -> out = x * sigmoid(.) fp32 NCHW
__global__ __launch_bounds__(256) void gemm_proj(const u16* __restrict__ A, const u16* __restrict__ Bw,
                                                 const float* __restrict__ bias, const float* __restrict__ xin,
                                                 float* __restrict__ outp) {
    __shared__ __align__(16) short As[128*64];
    __shared__ __align__(16) short Bs[128*64];
    f32x4 acc[4][4] = {};
    const int n0 = blockIdx.x * 128, m0 = blockIdx.y * 128;
    const int tid  = threadIdx.x;
    const int lane = tid & 63, wave = tid >> 6;
    const int wm = wave >> 1, wn = wave & 1;
    const int quad = lane >> 4, lr = lane & 15;
    for (int kt = 0; kt < DIM; kt += 64) {
        __syncthreads();
#pragma unroll
        for (int c = 0; c < 4; c++) {
            int idx = c*256 + tid;
            int r = idx >> 3, g = idx & 7;
            int so = r*64 + ((g ^ (r & 7)) << 3);
            *(uint4*)&As[so] = *(const uint4*)&A[(size_t)(m0 + r)*DIM + kt + g*8];
            *(uint4*)&Bs[so] = *(const uint4*)&Bw[(size_t)(n0 + r)*DIM + kt + g*8];
        }
        __syncthreads();
        mfma_tile(As, Bs, acc, wm, wn, quad, lr);
    }
#pragma unroll
    for (int in_ = 0; in_ < 4; in_++) {
        int col = n0 + wn*64 + in_*16 + lr;           // < 384
        float bcol = bias[col];
#pragma unroll
        for (int im = 0; im < 4; im++) {
            int rowb = m0 + wm*64 + im*16 + quad*4;
#pragma unroll
            for (int r = 0; r < 4; r++) {
                int grow = rowb + r;
                int bb = grow / NPIX;
                int pix = grow - bb*NPIX;
                float o = acc[im][in_][r] + bcol;
                float sg = 1.f / (1.f + __expf(-o));
                size_t xi = ((size_t)bb*DIM + col)*NPIX + pix;
                outp[xi] = xin[xi] * sg;
            }
        }
    }
}

// ---------------- agent pooling: 8x8 mean of q(bf16) -> agent [b][H][49][32] fp32 ----------------
__global__ __launch_bounds__(256) void pool_q(const u16* __restrict__ qb, float* __restrict__ agent) {
    int gt = blockIdx.x * 256 + threadIdx.x;          // < 32*12*49*32
    int d = gt & 31;
    int t2 = gt >> 5;
    int a = t2 % 49;
    int bh = t2 / 49;
    int ay = a / 7, ax = a % 7;
    const u16* qp = qb + (size_t)bh*NPIX*HD + d;
    float s = 0.f;
#pragma unroll
    for (int dy = 0; dy < 8; dy++)
#pragma unroll
        for (int dx = 0; dx < 8; dx++)
            s += bf2f(qp[(size_t)((ay*8 + dy)*56 + ax*8 + dx)*HD]);
    agent[gt] = s * (1.f/64.f);
}

// ---------------- stage 1: pixel-chunked partial softmax + PV ----------------
// scores tiny (|s| <~ 1): exp without max-subtraction is exact softmax, and partial
// numerator/denominator sums over pixel chunks combine by plain addition.
// grid: (14 chunks of 224 pixels) x (384 bh). K/V read exactly ONCE (was 13x).
#define S1_CHUNK  224
#define S1_NCHUNK 14          // 3136 / 224
#define S1_PSTR   228         // P_s row stride: 2-way-bank writes (free), rows 16B-aligned

__global__ __launch_bounds__(256) void stage1_part(const u16* __restrict__ kb, const u16* __restrict__ vb,
                                                   const float* __restrict__ agent, const float* __restrict__ pb1,
                                                   float* __restrict__ accv, float* __restrict__ accl) {
    __shared__ __align__(16) float ah_s[AGENTS*HD];        //  6272 B
    __shared__ __align__(16) float P_s[AGENTS*S1_PSTR];    // 44688 B, P transposed [a][pix]
    const int chunk = blockIdx.x;
    const int bh    = blockIdx.y;
    const int hh    = bh % HEADS;
    const int tid   = threadIdx.x;
    const int pix0  = chunk * S1_CHUNK;
    const float scale = 0.1767766952966369f;  // 32^-0.5

    for (int i = tid; i < AGENTS*HD; i += 256)
        ah_s[i] = agent[(size_t)bh*AGENTS*HD + i];
    __syncthreads();

    // phase A: one pixel per thread, 49 scores -> exp -> P_s[a][pix]
    if (tid < S1_CHUNK) {
        float kf[32];
        unpack_row32(kb + ((size_t)bh*NPIX + pix0 + tid)*HD, kf);
        const float* pbp = pb1 + (size_t)hh*AGENTS*NPIX + pix0 + tid;
        for (int a = 0; a < AGENTS; a++) {
            const float* ap = &ah_s[a*HD];                 // wave-uniform -> LDS broadcast
            float s0 = 0.f, s1 = 0.f, s2 = 0.f, s3 = 0.f;
#pragma unroll
            for (int d = 0; d < 32; d += 4) {
                s0 = fmaf(ap[d+0], kf[d+0], s0);
                s1 = fmaf(ap[d+1], kf[d+1], s1);
                s2 = fmaf(ap[d+2], kf[d+2], s2);
                s3 = fmaf(ap[d+3], kf[d+3], s3);
            }
            float s = ((s0+s1)+(s2+s3))*scale + pbp[(size_t)a*NPIX];
            P_s[a*S1_PSTR + tid] = __expf(s);
        }
    }
    __syncthreads();

    // partial denominators: l[a] = sum_pix P[a][pix]  (196 threads: a x 4 sub-stripes)
    if (tid < 196) {
        int a = tid >> 2, sub = tid & 3;
        const float* pp = &P_s[a*S1_PSTR + sub*56];
        float ls = 0.f;
        for (int k = 0; k < 56; k++) ls += pp[k];
        ls += __shfl_xor(ls, 1, 64);
        ls += __shfl_xor(ls, 2, 64);
        if (sub == 0) atomicAdd(&accl[(size_t)bh*AGENTS + a], ls);
    }

    // phase B: acc[a] += P[a][pix] * V[pix][d], thread (g,d) owns 7 groups of 4 pixels
    const int d = tid & 31, g = tid >> 5;                  // g: 0..7
    float acc[AGENTS];
#pragma unroll
    for (int a = 0; a < AGENTS; a++) acc[a] = 0.f;
    const u16* vp = vb + ((size_t)bh*NPIX + pix0)*HD + d;
    for (int p8 = 0; p8 < 7; p8++) {
        int pixl = p8*32 + g*4;
        float v0 = bf2f(vp[(size_t)(pixl+0)*HD]);
        float v1 = bf2f(vp[(size_t)(pixl+1)*HD]);
        float v2 = bf2f(vp[(size_t)(pixl+2)*HD]);
        float v3 = bf2f(vp[(size_t)(pixl+3)*HD]);
#pragma unroll
        for (int a = 0; a < AGENTS; a++) {
            f32x4 pq = *(const f32x4*)&P_s[a*S1_PSTR + pixl];   // wave-uniform addr -> broadcast
            acc[a] = fmaf(pq[0], v0, fmaf(pq[1], v1, fmaf(pq[2], v2, fmaf(pq[3], v3, acc[a]))));
        }
    }
    __syncthreads();   // all P_s reads done before aliasing it as reduction scratch

    // reduce 8 g-groups: pair-sum via shfl across half-wave, then 4-wave LDS reduce
#pragma unroll
    for (int a = 0; a < AGENTS; a++) acc[a] += __shfl_xor(acc[a], 32, 64);
    float* red = (float*)P_s;                              // [4][AGENTS][HD] = 25088 B, fits
    const int w = tid >> 6;
    if ((tid & 63) < 32) {
#pragma unroll
        for (int a = 0; a < AGENTS; a++) red[(w*AGENTS + a)*HD + d] = acc[a];
    }
    __syncthreads();
    for (int i = tid; i < AGENTS*HD; i += 256) {
        float s = red[i] + red[AGENTS*HD + i] + red[2*AGENTS*HD + i] + red[3*AGENTS*HD + i];
        atomicAdd(&accv[(size_t)bh*AGENTS*HD + i], s);
    }
}

__global__ __launch_bounds__(256) void stage1_final(const float* __restrict__ accv, const float* __restrict__ accl,
                                                    float* __restrict__ agentv) {
    int i = blockIdx.x * 256 + threadIdx.x;                // < 384*49*32
    agentv[i] = accv[i] / accl[i >> 5];
}

// ---------------- stage 2: o[pix,:] = softmax_a(scale*q.ah + ab1) @ agent_v -> obuf bf16 ----------------
__global__ __launch_bounds__(256) void stage2(const u16* __restrict__ qb, const float* __restrict__ agent,
                                              const float* __restrict__ agentv, const float* __restrict__ ab1,
                                              u16* __restrict__ obuf) {
    __shared__ float ah_s[AGENTS*32];
    __shared__ float av_s[AGENTS*32];
    const int b = blockIdx.z, hh = blockIdx.y, chunk = blockIdx.x;
    const int bh = b*HEADS + hh;
    for (int i = threadIdx.x; i < AGENTS*32; i += 256) {
        ah_s[i] = agent[(size_t)bh*AGENTS*HD + i];
        av_s[i] = agentv[(size_t)bh*AGENTS*HD + i];
    }
    __syncthreads();
    int pix = chunk*256 + threadIdx.x;
    if (pix >= NPIX) return;
    const float scale = 0.1767766952966369f;
    float qf[32];
    unpack_row32(qb + ((size_t)bh*NPIX + pix)*HD, qf);
    float oacc[32];
#pragma unroll
    for (int d = 0; d < 32; d++) oacc[d] = 0.f;
    float l = 0.f;
    const float* abp = ab1 + (size_t)hh*AGENTS*NPIX + pix;
    for (int a = 0; a < AGENTS; a++) {
        float s = 0.f;
#pragma unroll
        for (int d = 0; d < 32; d++) s = fmaf(qf[d], ah_s[a*32 + d], s);
        s = s * scale + abp[(size_t)a*NPIX];
        float p = __expf(s);
        l += p;
#pragma unroll
        for (int d = 0; d < 32; d++) oacc[d] = fmaf(p, av_s[a*32 + d], oacc[d]);
    }
    float inv = 1.f / l;
    u16* op = obuf + ((size_t)b*NPIX + pix)*DIM + hh*HD;
#pragma unroll
    for (int d2 = 0; d2 < 16; d2++) {
        u32 lo = f2bf(oacc[2*d2] * inv);
        u32 hi = f2bf(oacc[2*d2 + 1] * inv);
        ((u32*)op)[d2] = lo | (hi << 16);
    }
}

// ---------------- depthwise 3x3 conv on V (fp32 weights), added into obuf (bf16) ----------------
__global__ __launch_bounds__(256) void dwconv_add(const u16* __restrict__ vb, const float* __restrict__ dwcw,
                                                  const float* __restrict__ dwcb, u16* __restrict__ obuf) {
    const int chunk = blockIdx.x;       // 0..97 (32 pixels each)
    const int hh = blockIdx.y, b = blockIdx.z;
    const int dd = threadIdx.x & 31, pg = threadIdx.x >> 5;
    const int ch = hh*HD + dd;
    float wgt[9];
#pragma unroll
    for (int i = 0; i < 9; i++) wgt[i] = dwcw[ch*9 + i];
    float bbias = dwcb[ch];
    const u16* vp = vb + (size_t)(b*HEADS + hh)*NPIX*HD + dd;
#pragma unroll
    for (int i = 0; i < 4; i++) {
        int pix = chunk*32 + i*8 + pg;
        int y = pix / 56, x0 = pix - y*56;
        float s = bbias;
#pragma unroll
        for (int dy = 0; dy < 3; dy++) {
            int yy = y + dy - 1;
            if (yy < 0 || yy > 55) continue;
#pragma unroll
            for (int dx = 0; dx < 3; dx++) {
                int xx = x0 + dx - 1;
                if (xx < 0 || xx > 55) continue;
                s = fmaf(wgt[dy*3 + dx], bf2f(vp[(size_t)(yy*56 + xx)*HD]), s);
            }
        }
        size_t oi = ((size_t)b*NPIX + pix)*DIM + ch;
        obuf[oi] = f2bf(bf2f(obuf[oi]) + s);
    }
}

// ---------------- launch ----------------
extern "C" void kernel_launch(void* const* d_in, const int* in_sizes, int n_in,
                              void* d_out, int out_size, void* d_ws, size_t ws_size,
                              hipStream_t stream) {
    const float* x     = (const float*)d_in[0];
    const float* qkvw  = (const float*)d_in[1];
    const float* qkvb  = (const float*)d_in[2];
    const float* projw = (const float*)d_in[3];
    const float* projb = (const float*)d_in[4];
    const float* anb   = (const float*)d_in[5];
    const float* nab   = (const float*)d_in[6];
    const float* dwcw  = (const float*)d_in[7];
    const float* dwcb  = (const float*)d_in[8];
    float* out = (float*)d_out;

    // d_ws layout (221.6 MiB total)
    char* w = (char*)d_ws;
    const size_t SZ_BNC = (size_t)BATCH*NPIX*DIM*2;          // 77,070,336 B (bf16)
    u16* qb     = (u16*)w;  w += SZ_BNC;
    u16* kb     = (u16*)w;  w += SZ_BNC;                     // reused as obuf after stage1
    u16* vb     = (u16*)w;  w += SZ_BNC;
    u16* qkvwT  = (u16*)w;  w += (size_t)1152*384*2;
    u16* projwT = (u16*)w;  w += (size_t)384*384*2;
    u16* obuf   = kb;

    // stage-only fp32 buffers live in d_out (147 MB; all dead before gemm_proj rewrites d_out)
    char* o = (char*)d_out;
    float* pb1    = (float*)o; o += (size_t)HEADS*AGENTS*NPIX*4;      //  7.38 MB
    float* ab1    = (float*)o; o += (size_t)HEADS*AGENTS*NPIX*4;      //  7.38 MB
    float* agent  = (float*)o; o += (size_t)BATCH*HEADS*AGENTS*HD*4;  //  2.41 MB
    float* agentv = (float*)o; o += (size_t)BATCH*HEADS*AGENTS*HD*4;  //  2.41 MB
    float* accv   = (float*)o; o += (size_t)BATCH*HEADS*AGENTS*HD*4;  //  2.41 MB (stage1 partial numerators)
    float* accl   = (float*)o; o += (size_t)BATCH*HEADS*AGENTS*4;     //  0.08 MB (stage1 partial denominators)

    const int nacc = BATCH*HEADS*AGENTS*(HD + 1);            // accv + accl, contiguous

    transpose_mat<<<dim3(18, 6),     256, 0, stream>>>(qkvw, qkvwT, 384, 1152);
    transpose_mat<<<dim3(6, 6),      256, 0, stream>>>(projw, projwT, 384, 384);
    upsample_bias<<<dim3(7203),      256, 0, stream>>>(anb, pb1);
    upsample_bias<<<dim3(7203),      256, 0, stream>>>(nab, ab1);
    zero_init    <<<dim3((nacc + 255)/256), 256, 0, stream>>>(accv, nacc);
    gemm_qkv     <<<dim3(9, 25, 32), 256, 0, stream>>>(x, qkvwT, qkvb, qb, kb, vb);
    pool_q       <<<dim3(2352),      256, 0, stream>>>(qb, agent);
    stage1_part  <<<dim3(S1_NCHUNK, BATCH*HEADS), 256, 0, stream>>>(kb, vb, agent, pb1, accv, accl);
    stage1_final <<<dim3(2352),      256, 0, stream>>>(accv, accl, agentv);
    stage2       <<<dim3(13, 12, 32),256, 0, stream>>>(qb, agent, agentv, ab1, obuf);
    dwconv_add   <<<dim3(98, 12, 32),256, 0, stream>>>(vb, dwcw, dwcb, obuf);
    gemm_proj    <<<dim3(3, 784),    256, 0, stream>>>(obuf, projwT, projb, x, out);
}

// Round 3
// 1359.846 us; speedup vs baseline: 1.9798x; 1.0469x over previous
//
#include <hip/hip_runtime.h>

// ---------------- problem constants ----------------
#define DIM    384
#define HEADS  12
#define NPIX   3136      // 56*56
#define BATCH  32
#define AGENTS 49
#define HD     32

typedef unsigned short u16;
typedef unsigned int   u32;
typedef __attribute__((ext_vector_type(8))) short short8;   // 8 bf16 (4 VGPRs)
typedef __attribute__((ext_vector_type(4))) float f32x4;

__device__ __forceinline__ float bf2f(u16 u) { return __uint_as_float(((u32)u) << 16); }
__device__ __forceinline__ u16 f2bf(float f) {
    u32 i = __float_as_uint(f);
    u32 r = i + 0x7fffu + ((i >> 16) & 1u);   // round-to-nearest-even
    return (u16)(r >> 16);
}

// unpack 32 contiguous bf16 -> 32 floats (16B-aligned source)
__device__ __forceinline__ void unpack_row32(const u16* p, float* f) {
    const uint4* q = (const uint4*)p;
#pragma unroll
    for (int i = 0; i < 4; i++) {
        uint4 u = q[i];
        u32 w0 = u.x, w1 = u.y, w2 = u.z, w3 = u.w;
        f[i*8+0] = __uint_as_float(w0 << 16); f[i*8+1] = __uint_as_float(w0 & 0xffff0000u);
        f[i*8+2] = __uint_as_float(w1 << 16); f[i*8+3] = __uint_as_float(w1 & 0xffff0000u);
        f[i*8+4] = __uint_as_float(w2 << 16); f[i*8+5] = __uint_as_float(w2 & 0xffff0000u);
        f[i*8+6] = __uint_as_float(w3 << 16); f[i*8+7] = __uint_as_float(w3 & 0xffff0000u);
    }
}

// generic: src fp32 [R][C] -> dst bf16 [C][R]  (R, C multiples of 64)
__global__ __launch_bounds__(256) void transpose_mat(const float* __restrict__ src, u16* __restrict__ dst,
                                                     int R, int C) {
    __shared__ u16 tile[64][65];
    int c0 = blockIdx.x * 64, r0 = blockIdx.y * 64;
    int t0 = threadIdx.x & 63, t1 = threadIdx.x >> 6;
#pragma unroll
    for (int i = 0; i < 16; i++) {
        int r = t1 + i*4;
        tile[t0][r] = f2bf(src[(size_t)(r0 + r)*C + c0 + t0]);
    }
    __syncthreads();
#pragma unroll
    for (int i = 0; i < 16; i++) {
        int c = t1 + i*4;
        dst[(size_t)(c0 + c)*R + r0 + t0] = tile[c][t0];
    }
}

// ---------------- x NCHW fp32 -> xT [b][pix][384] bf16 (one-time convert+transpose) ----------------
__global__ __launch_bounds__(256) void convert_x(const float* __restrict__ x, u16* __restrict__ xT) {
    __shared__ float tile[64][65];     // [pix][ch], pad -> conflict-free col writes
    const int p0 = blockIdx.x * 64;
    const int c0 = blockIdx.y * 64;
    const int b  = blockIdx.z;
    const int t0 = threadIdx.x & 63, t1 = threadIdx.x >> 6;
#pragma unroll
    for (int i = 0; i < 16; i++) {
        int ch = t1 + i*4;
        tile[t0][ch] = x[((size_t)b*DIM + c0 + ch)*NPIX + p0 + t0];   // coalesced 256B rows
    }
    __syncthreads();
    const int cb = threadIdx.x & 7, r = threadIdx.x >> 3;   // r in [0,32)
#pragma unroll
    for (int half = 0; half < 2; half++) {
        int rr = r + half*32;
        const float* tp = &tile[rr][cb*8];
        u32 w0 = f2bf(tp[0]) | ((u32)f2bf(tp[1]) << 16);
        u32 w1 = f2bf(tp[2]) | ((u32)f2bf(tp[3]) << 16);
        u32 w2 = f2bf(tp[4]) | ((u32)f2bf(tp[5]) << 16);
        u32 w3 = f2bf(tp[6]) | ((u32)f2bf(tp[7]) << 16);
        *(uint4*)&xT[((size_t)b*NPIX + p0 + rr)*DIM + c0 + cb*8] = make_uint4(w0, w1, w2, w3);
    }
}

// ---------------- bilinear bias upsample 7x7 -> 56x56 (fp32 -> fp32) ----------------
__global__ __launch_bounds__(256) void upsample_bias(const float* __restrict__ src, float* __restrict__ dst) {
    int idx = blockIdx.x * 256 + threadIdx.x;          // < 12*49*3136
    int xo = idx % 56; int t = idx / 56;
    int yo = t % 56;   int ha = t / 56;                // h*49 + a
    float fy = yo * 0.125f - 0.4375f;
    float fx = xo * 0.125f - 0.4375f;
    float y0f = floorf(fy), x0f = floorf(fx);
    float wy = fy - y0f, wx = fx - x0f;
    int y0 = (int)y0f, x0 = (int)x0f;
    int y0c = max(y0, 0), y1c = min(y0 + 1, 6);
    int x0c = max(x0, 0), x1c = min(x0 + 1, 6);
    const float* sp = src + (size_t)ha * 49;
    float v00 = sp[y0c*7 + x0c], v01 = sp[y0c*7 + x1c];
    float v10 = sp[y1c*7 + x0c], v11 = sp[y1c*7 + x1c];
    dst[idx] = (1.f-wy)*((1.f-wx)*v00 + wx*v01) + wy*((1.f-wx)*v10 + wx*v11);
}

// ---------------- zero-init for stage1 partial accumulators ----------------
__global__ __launch_bounds__(256) void zero_init(float* __restrict__ p, int n) {
    int i = blockIdx.x * 256 + threadIdx.x;
    if (i < n) p[i] = 0.f;
}

// ---------------- shared MFMA fragment compute (tiles staged in As/Bs, XOR swizzle) ----------------
__device__ __forceinline__ void mfma_tile(const short* As, const short* Bs, f32x4 acc[4][4],
                                          int wm, int wn, int quad, int lr) {
#pragma unroll
    for (int ks = 0; ks < 2; ks++) {
        int g = ks*4 + quad;
        short8 af[4], bg[4];
#pragma unroll
        for (int im = 0; im < 4; im++) {
            int r = wm*64 + im*16 + lr;
            af[im] = *(const short8*)&As[r*64 + ((g ^ (r & 7)) << 3)];
        }
#pragma unroll
        for (int in_ = 0; in_ < 4; in_++) {
            int r = wn*64 + in_*16 + lr;
            bg[in_] = *(const short8*)&Bs[r*64 + ((g ^ (r & 7)) << 3)];
        }
#pragma unroll
        for (int im = 0; im < 4; im++)
#pragma unroll
            for (int in_ = 0; in_ < 4; in_++)
                acc[im][in_] = __builtin_amdgcn_mfma_f32_16x16x32_bf16(af[im], bg[in_], acc[im][in_], 0, 0, 0);
    }
}

// QKV GEMM: xT(bf16)[b][3136][384] @ qkvwT(bf16)[1152][384]^T -> per-head q/k/v bf16.
// XCD chunk-swizzle: the 9 n-tiles sharing one (p,b) A-slice land consecutively on ONE XCD.
__global__ __launch_bounds__(256) void gemm_qkv(const u16* __restrict__ xT, const u16* __restrict__ Bw,
                                                const float* __restrict__ bias,
                                                u16* __restrict__ qb, u16* __restrict__ kb, u16* __restrict__ vb) {
    __shared__ __align__(16) short As[128*64];
    __shared__ __align__(16) short Bs[128*64];
    f32x4 acc[4][4] = {};
    const int l  = blockIdx.x + 9*(blockIdx.y + 25*blockIdx.z);   // hardware linear id (x fastest)
    const int k8 = l & 7, j = l >> 3;          // j in [0,900)
    const int c  = (j/9)*8 + k8;               // chunk = p + 25*b, [0,800)
    const int i9 = j - (j/9)*9;                // n-tile [0,9)
    const int n0 = i9 * 128;
    const int p0 = (c % 25) * 128;
    const int bb = c / 25;
    const int tid  = threadIdx.x;
    const int lane = tid & 63, wave = tid >> 6;
    const int wm = wave >> 1, wn = wave & 1;
    const int quad = lane >> 4, lr = lane & 15;

    for (int kt = 0; kt < DIM; kt += 64) {
        __syncthreads();
#pragma unroll
        for (int c2 = 0; c2 < 4; c2++) {
            int idx = c2*256 + tid;
            int r = idx >> 3, g = idx & 7;
            int so = r*64 + ((g ^ (r & 7)) << 3);
            // tail tiles (p0=3072) overread into next batch / d_out slack: rows masked at epilogue
            *(uint4*)&As[so] = *(const uint4*)&xT[((size_t)bb*NPIX + p0 + r)*DIM + kt + g*8];
            *(uint4*)&Bs[so] = *(const uint4*)&Bw[(size_t)(n0 + r)*DIM + kt + g*8];
        }
        __syncthreads();
        mfma_tile(As, Bs, acc, wm, wn, quad, lr);
    }
    // --- epilogue: scatter into per-head q/k/v (bf16) ---
#pragma unroll
    for (int in_ = 0; in_ < 4; in_++) {
        int col = n0 + wn*64 + in_*16 + lr;           // < 1152
        int which = col / 384;
        int ch = col - which*384;
        int head = ch >> 5, d = ch & 31;
        float bcol = bias[col];
        u16* dstp = (which == 0) ? qb : ((which == 1) ? kb : vb);
#pragma unroll
        for (int im = 0; im < 4; im++) {
            int prow = p0 + wm*64 + im*16 + quad*4;
#pragma unroll
            for (int r = 0; r < 4; r++) {
                int pix = prow + r;
                if (pix < NPIX) {
                    float v = acc[im][in_][r] + bcol;
                    dstp[((size_t)(bb*HEADS + head)*NPIX + pix)*HD + d] = f2bf(v);
                }
            }
        }
    }
}

// proj GEMM: obuf(bf16)[100352][384] @ projwT(bf16)[384][384]^T + bias -> out = x * sigmoid(.) fp32 NCHW
__global__ __launch_bounds__(256) void gemm_proj(const u16* __restrict__ A, const u16* __restrict__ Bw,
                                                 const float* __restrict__ bias, const float* __restrict__ xin,
                                                 float* __restrict__ outp) {
    __shared__ __align__(16) short As[128*64];
    __shared__ __align__(16) short Bs[128*64];
    f32x4 acc[4][4] = {};
    const int l  = blockIdx.x + 3*blockIdx.y;  // [0,2352)
    const int k8 = l & 7, j = l >> 3;          // j in [0,294)
    const int c  = (j/3)*8 + k8;               // m-chunk [0,784)
    const int i3 = j - (j/3)*3;                // n-tile [0,3)
    const int n0 = i3*128, m0 = c*128;
    const int tid  = threadIdx.x;
    const int lane = tid & 63, wave = tid >> 6;
    const int wm = wave >> 1, wn = wave & 1;
    const int quad = lane >> 4, lr = lane & 15;
    for (int kt = 0; kt < DIM; kt += 64) {
        __syncthreads();
#pragma unroll
        for (int c2 = 0; c2 < 4; c2++) {
            int idx = c2*256 + tid;
            int r = idx >> 3, g = idx & 7;
            int so = r*64 + ((g ^ (r & 7)) << 3);
            *(uint4*)&As[so] = *(const uint4*)&A[(size_t)(m0 + r)*DIM + kt + g*8];
            *(uint4*)&Bs[so] = *(const uint4*)&Bw[(size_t)(n0 + r)*DIM + kt + g*8];
        }
        __syncthreads();
        mfma_tile(As, Bs, acc, wm, wn, quad, lr);
    }
#pragma unroll
    for (int in_ = 0; in_ < 4; in_++) {
        int col = n0 + wn*64 + in_*16 + lr;           // < 384
        float bcol = bias[col];
#pragma unroll
        for (int im = 0; im < 4; im++) {
            int rowb = m0 + wm*64 + im*16 + quad*4;
#pragma unroll
            for (int r = 0; r < 4; r++) {
                int grow = rowb + r;
                int bb = grow / NPIX;
                int pix = grow - bb*NPIX;
                float o = acc[im][in_][r] + bcol;
                float sg = 1.f / (1.f + __expf(-o));
                size_t xi = ((size_t)bb*DIM + col)*NPIX + pix;
                outp[xi] = xin[xi] * sg;
            }
        }
    }
}

// ---------------- agent pooling: 8x8 mean of q(bf16) -> agent [b][H][49][32] fp32 ----------------
__global__ __launch_bounds__(256) void pool_q(const u16* __restrict__ qb, float* __restrict__ agent) {
    int gt = blockIdx.x * 256 + threadIdx.x;          // < 32*12*49*32
    int d = gt & 31;
    int t2 = gt >> 5;
    int a = t2 % 49;
    int bh = t2 / 49;
    int ay = a / 7, ax = a % 7;
    const u16* qp = qb + (size_t)bh*NPIX*HD + d;
    float s = 0.f;
#pragma unroll
    for (int dy = 0; dy < 8; dy++)
#pragma unroll
        for (int dx = 0; dx < 8; dx++)
            s += bf2f(qp[(size_t)((ay*8 + dy)*56 + ax*8 + dx)*HD]);
    agent[gt] = s * (1.f/64.f);
}

// ---------------- stage 1: pixel-chunked partial softmax + PV ----------------
#define S1_CHUNK  224
#define S1_NCHUNK 14          // 3136 / 224
#define S1_PSTR   228         // P_s row stride: 2-way-bank writes (free), rows 16B-aligned

__global__ __launch_bounds__(256) void stage1_part(const u16* __restrict__ kb, const u16* __restrict__ vb,
                                                   const float* __restrict__ agent, const float* __restrict__ pb1,
                                                   float* __restrict__ accv, float* __restrict__ accl) {
    __shared__ __align__(16) float ah_s[AGENTS*HD];        //  6272 B
    __shared__ __align__(16) float P_s[AGENTS*S1_PSTR];    // 44688 B, P transposed [a][pix]
    const int chunk = blockIdx.x;
    const int bh    = blockIdx.y;
    const int hh    = bh % HEADS;
    const int tid   = threadIdx.x;
    const int pix0  = chunk * S1_CHUNK;
    const float scale = 0.1767766952966369f;  // 32^-0.5

    for (int i = tid; i < AGENTS*HD; i += 256)
        ah_s[i] = agent[(size_t)bh*AGENTS*HD + i];
    __syncthreads();

    // phase A: one pixel per thread, 49 scores -> exp -> P_s[a][pix]
    if (tid < S1_CHUNK) {
        float kf[32];
        unpack_row32(kb + ((size_t)bh*NPIX + pix0 + tid)*HD, kf);
        const float* pbp = pb1 + (size_t)hh*AGENTS*NPIX + pix0 + tid;
        for (int a = 0; a < AGENTS; a++) {
            const float* ap = &ah_s[a*HD];                 // wave-uniform -> LDS broadcast
            float s0 = 0.f, s1 = 0.f, s2 = 0.f, s3 = 0.f;
#pragma unroll
            for (int d = 0; d < 32; d += 4) {
                s0 = fmaf(ap[d+0], kf[d+0], s0);
                s1 = fmaf(ap[d+1], kf[d+1], s1);
                s2 = fmaf(ap[d+2], kf[d+2], s2);
                s3 = fmaf(ap[d+3], kf[d+3], s3);
            }
            float s = ((s0+s1)+(s2+s3))*scale + pbp[(size_t)a*NPIX];
            P_s[a*S1_PSTR + tid] = __expf(s);
        }
    }
    __syncthreads();

    // partial denominators: l[a] = sum_pix P[a][pix]  (196 threads: a x 4 sub-stripes)
    if (tid < 196) {
        int a = tid >> 2, sub = tid & 3;
        const float* pp = &P_s[a*S1_PSTR + sub*56];
        float ls = 0.f;
        for (int k = 0; k < 56; k++) ls += pp[k];
        ls += __shfl_xor(ls, 1, 64);
        ls += __shfl_xor(ls, 2, 64);
        if (sub == 0) atomicAdd(&accl[(size_t)bh*AGENTS + a], ls);
    }

    // phase B: acc[a] += P[a][pix] * V[pix][d], thread (g,d) owns 7 groups of 4 pixels
    const int d = tid & 31, g = tid >> 5;                  // g: 0..7
    float acc[AGENTS];
#pragma unroll
    for (int a = 0; a < AGENTS; a++) acc[a] = 0.f;
    const u16* vp = vb + ((size_t)bh*NPIX + pix0)*HD + d;
    for (int p8 = 0; p8 < 7; p8++) {
        int pixl = p8*32 + g*4;
        float v0 = bf2f(vp[(size_t)(pixl+0)*HD]);
        float v1 = bf2f(vp[(size_t)(pixl+1)*HD]);
        float v2 = bf2f(vp[(size_t)(pixl+2)*HD]);
        float v3 = bf2f(vp[(size_t)(pixl+3)*HD]);
#pragma unroll
        for (int a = 0; a < AGENTS; a++) {
            f32x4 pq = *(const f32x4*)&P_s[a*S1_PSTR + pixl];   // wave-uniform addr -> broadcast
            acc[a] = fmaf(pq[0], v0, fmaf(pq[1], v1, fmaf(pq[2], v2, fmaf(pq[3], v3, acc[a]))));
        }
    }
    __syncthreads();   // all P_s reads done before aliasing it as reduction scratch

    // reduce 8 g-groups: pair-sum via shfl across half-wave, then 4-wave LDS reduce
#pragma unroll
    for (int a = 0; a < AGENTS; a++) acc[a] += __shfl_xor(acc[a], 32, 64);
    float* red = (float*)P_s;                              // [4][AGENTS][HD] = 25088 B, fits
    const int w = tid >> 6;
    if ((tid & 63) < 32) {
#pragma unroll
        for (int a = 0; a < AGENTS; a++) red[(w*AGENTS + a)*HD + d] = acc[a];
    }
    __syncthreads();
    for (int i = tid; i < AGENTS*HD; i += 256) {
        float s = red[i] + red[AGENTS*HD + i] + red[2*AGENTS*HD + i] + red[3*AGENTS*HD + i];
        atomicAdd(&accv[(size_t)bh*AGENTS*HD + i], s);
    }
}

__global__ __launch_bounds__(256) void stage1_final(const float* __restrict__ accv, const float* __restrict__ accl,
                                                    float* __restrict__ agentv) {
    int i = blockIdx.x * 256 + threadIdx.x;                // < 384*49*32
    agentv[i] = accv[i] / accl[i >> 5];
}

// ---------------- stage 2: o[pix,:] = softmax_a(scale*q.ah + ab1) @ agent_v -> obuf bf16 ----------------
__global__ __launch_bounds__(256) void stage2(const u16* __restrict__ qb, const float* __restrict__ agent,
                                              const float* __restrict__ agentv, const float* __restrict__ ab1,
                                              u16* __restrict__ obuf) {
    __shared__ float ah_s[AGENTS*32];
    __shared__ float av_s[AGENTS*32];
    const int b = blockIdx.z, hh = blockIdx.y, chunk = blockIdx.x;
    const int bh = b*HEADS + hh;
    for (int i = threadIdx.x; i < AGENTS*32; i += 256) {
        ah_s[i] = agent[(size_t)bh*AGENTS*HD + i];
        av_s[i] = agentv[(size_t)bh*AGENTS*HD + i];
    }
    __syncthreads();
    int pix = chunk*256 + threadIdx.x;
    if (pix >= NPIX) return;
    const float scale = 0.1767766952966369f;
    float qf[32];
    unpack_row32(qb + ((size_t)bh*NPIX + pix)*HD, qf);
    float oacc[32];
#pragma unroll
    for (int d = 0; d < 32; d++) oacc[d] = 0.f;
    float l = 0.f;
    const float* abp = ab1 + (size_t)hh*AGENTS*NPIX + pix;
    for (int a = 0; a < AGENTS; a++) {
        float s = 0.f;
#pragma unroll
        for (int d = 0; d < 32; d++) s = fmaf(qf[d], ah_s[a*32 + d], s);
        s = s * scale + abp[(size_t)a*NPIX];
        float p = __expf(s);
        l += p;
#pragma unroll
        for (int d = 0; d < 32; d++) oacc[d] = fmaf(p, av_s[a*32 + d], oacc[d]);
    }
    float inv = 1.f / l;
    u16* op = obuf + ((size_t)b*NPIX + pix)*DIM + hh*HD;
#pragma unroll
    for (int d2 = 0; d2 < 16; d2++) {
        u32 lo = f2bf(oacc[2*d2] * inv);
        u32 hi = f2bf(oacc[2*d2 + 1] * inv);
        ((u32*)op)[d2] = lo | (hi << 16);
    }
}

// ---------------- depthwise 3x3 conv on V (fp32 weights), added into obuf (bf16) ----------------
__global__ __launch_bounds__(256) void dwconv_add(const u16* __restrict__ vb, const float* __restrict__ dwcw,
                                                  const float* __restrict__ dwcb, u16* __restrict__ obuf) {
    const int chunk = blockIdx.x;       // 0..97 (32 pixels each)
    const int hh = blockIdx.y, b = blockIdx.z;
    const int dd = threadIdx.x & 31, pg = threadIdx.x >> 5;
    const int ch = hh*HD + dd;
    float wgt[9];
#pragma unroll
    for (int i = 0; i < 9; i++) wgt[i] = dwcw[ch*9 + i];
    float bbias = dwcb[ch];
    const u16* vp = vb + (size_t)(b*HEADS + hh)*NPIX*HD + dd;
#pragma unroll
    for (int i = 0; i < 4; i++) {
        int pix = chunk*32 + i*8 + pg;
        int y = pix / 56, x0 = pix - y*56;
        float s = bbias;
#pragma unroll
        for (int dy = 0; dy < 3; dy++) {
            int yy = y + dy - 1;
            if (yy < 0 || yy > 55) continue;
#pragma unroll
            for (int dx = 0; dx < 3; dx++) {
                int xx = x0 + dx - 1;
                if (xx < 0 || xx > 55) continue;
                s = fmaf(wgt[dy*3 + dx], bf2f(vp[(size_t)(yy*56 + xx)*HD]), s);
            }
        }
        size_t oi = ((size_t)b*NPIX + pix)*DIM + ch;
        obuf[oi] = f2bf(bf2f(obuf[oi]) + s);
    }
}

// ---------------- launch ----------------
extern "C" void kernel_launch(void* const* d_in, const int* in_sizes, int n_in,
                              void* d_out, int out_size, void* d_ws, size_t ws_size,
                              hipStream_t stream) {
    const float* x     = (const float*)d_in[0];
    const float* qkvw  = (const float*)d_in[1];
    const float* qkvb  = (const float*)d_in[2];
    const float* projw = (const float*)d_in[3];
    const float* projb = (const float*)d_in[4];
    const float* anb   = (const float*)d_in[5];
    const float* nab   = (const float*)d_in[6];
    const float* dwcw  = (const float*)d_in[7];
    const float* dwcb  = (const float*)d_in[8];
    float* out = (float*)d_out;

    // d_ws layout (221.6 MiB total)
    char* w = (char*)d_ws;
    const size_t SZ_BNC = (size_t)BATCH*NPIX*DIM*2;          // 77,070,336 B (bf16)
    u16* qb     = (u16*)w;  w += SZ_BNC;
    u16* kb     = (u16*)w;  w += SZ_BNC;                     // reused as obuf after stage1
    u16* vb     = (u16*)w;  w += SZ_BNC;
    u16* qkvwT  = (u16*)w;  w += (size_t)1152*384*2;
    u16* projwT = (u16*)w;  w += (size_t)384*384*2;
    u16* obuf   = kb;

    // stage-only buffers live in d_out (147 MB; all dead before gemm_proj rewrites d_out)
    char* o = (char*)d_out;
    float* pb1    = (float*)o; o += (size_t)HEADS*AGENTS*NPIX*4;      //  7.38 MB
    float* ab1    = (float*)o; o += (size_t)HEADS*AGENTS*NPIX*4;      //  7.38 MB
    float* agent  = (float*)o; o += (size_t)BATCH*HEADS*AGENTS*HD*4;  //  2.41 MB
    float* agentv = (float*)o; o += (size_t)BATCH*HEADS*AGENTS*HD*4;  //  2.41 MB
    float* accv   = (float*)o; o += (size_t)BATCH*HEADS*AGENTS*HD*4;  //  2.41 MB
    float* accl   = (float*)o; o += (size_t)BATCH*HEADS*AGENTS*4;     //  0.08 MB
    u16*   xT     = (u16*)o;   o += SZ_BNC;                           // 77.07 MB (total ~99 MB + tail slack)

    const int nacc = BATCH*HEADS*AGENTS*(HD + 1);            // accv + accl, contiguous

    convert_x    <<<dim3(49, 6, 32), 256, 0, stream>>>(x, xT);
    transpose_mat<<<dim3(18, 6),     256, 0, stream>>>(qkvw, qkvwT, 384, 1152);
    transpose_mat<<<dim3(6, 6),      256, 0, stream>>>(projw, projwT, 384, 384);
    upsample_bias<<<dim3(7203),      256, 0, stream>>>(anb, pb1);
    upsample_bias<<<dim3(7203),      256, 0, stream>>>(nab, ab1);
    zero_init    <<<dim3((nacc + 255)/256), 256, 0, stream>>>(accv, nacc);
    gemm_qkv     <<<dim3(9, 25, 32), 256, 0, stream>>>(xT, qkvwT, qkvb, qb, kb, vb);
    pool_q       <<<dim3(2352),      256, 0, stream>>>(qb, agent);
    stage1_part  <<<dim3(S1_NCHUNK, BATCH*HEADS), 256, 0, stream>>>(kb, vb, agent, pb1, accv, accl);
    stage1_final <<<dim3(2352),      256, 0, stream>>>(accv, accl, agentv);
    stage2       <<<dim3(13, 12, 32),256, 0, stream>>>(qb, agent, agentv, ab1, obuf);
    dwconv_add   <<<dim3(98, 12, 32),256, 0, stream>>>(vb, dwcw, dwcb, obuf);
    gemm_proj    <<<dim3(3, 784),    256, 0, stream>>>(obuf, projwT, projb, x, out);
}

// Round 5
// 1347.545 us; speedup vs baseline: 1.9979x; 1.0091x over previous
//
#include <hip/hip_runtime.h>

// ---------------- problem constants ----------------
#define DIM    384
#define HEADS  12
#define NPIX   3136      // 56*56
#define BATCH  32
#define AGENTS 49
#define HD     32

typedef unsigned short u16;
typedef unsigned int   u32;
typedef __attribute__((ext_vector_type(8))) short short8;   // 8 bf16 (4 VGPRs)
typedef __attribute__((ext_vector_type(4))) float f32x4;

__device__ __forceinline__ float bf2f(u16 u) { return __uint_as_float(((u32)u) << 16); }
__device__ __forceinline__ u16 f2bf(float f) {
    u32 i = __float_as_uint(f);
    u32 r = i + 0x7fffu + ((i >> 16) & 1u);   // round-to-nearest-even
    return (u16)(r >> 16);
}

// async global->LDS, 16B per lane; LDS dest = wave-uniform base + lane*16 (linear)
__device__ __forceinline__ void glds16(const void* g, void* l) {
    __builtin_amdgcn_global_load_lds((const __attribute__((address_space(1))) void*)g,
                                     (__attribute__((address_space(3))) void*)l, 16, 0, 0);
}

// unpack 32 contiguous bf16 -> 32 floats (16B-aligned source)
__device__ __forceinline__ void unpack_row32(const u16* p, float* f) {
    const uint4* q = (const uint4*)p;
#pragma unroll
    for (int i = 0; i < 4; i++) {
        uint4 u = q[i];
        u32 w0 = u.x, w1 = u.y, w2 = u.z, w3 = u.w;
        f[i*8+0] = __uint_as_float(w0 << 16); f[i*8+1] = __uint_as_float(w0 & 0xffff0000u);
        f[i*8+2] = __uint_as_float(w1 << 16); f[i*8+3] = __uint_as_float(w1 & 0xffff0000u);
        f[i*8+4] = __uint_as_float(w2 << 16); f[i*8+5] = __uint_as_float(w2 & 0xffff0000u);
        f[i*8+6] = __uint_as_float(w3 << 16); f[i*8+7] = __uint_as_float(w3 & 0xffff0000u);
    }
}

// generic: src fp32 [R][C] -> dst bf16 [C][R]  (R, C multiples of 64)
__global__ __launch_bounds__(256) void transpose_mat(const float* __restrict__ src, u16* __restrict__ dst,
                                                     int R, int C) {
    __shared__ u16 tile[64][65];
    int c0 = blockIdx.x * 64, r0 = blockIdx.y * 64;
    int t0 = threadIdx.x & 63, t1 = threadIdx.x >> 6;
#pragma unroll
    for (int i = 0; i < 16; i++) {
        int r = t1 + i*4;
        tile[t0][r] = f2bf(src[(size_t)(r0 + r)*C + c0 + t0]);
    }
    __syncthreads();
#pragma unroll
    for (int i = 0; i < 16; i++) {
        int c = t1 + i*4;
        dst[(size_t)(c0 + c)*R + r0 + t0] = tile[c][t0];
    }
}

// ---------------- x NCHW fp32 -> xT [b][pix][384] bf16 (one-time convert+transpose) ----------------
__global__ __launch_bounds__(256) void convert_x(const float* __restrict__ x, u16* __restrict__ xT) {
    __shared__ float tile[64][65];     // [pix][ch], pad -> conflict-free col writes
    const int p0 = blockIdx.x * 64;
    const int c0 = blockIdx.y * 64;
    const int b  = blockIdx.z;
    const int t0 = threadIdx.x & 63, t1 = threadIdx.x >> 6;
#pragma unroll
    for (int i = 0; i < 16; i++) {
        int ch = t1 + i*4;
        tile[t0][ch] = x[((size_t)b*DIM + c0 + ch)*NPIX + p0 + t0];   // coalesced 256B rows
    }
    __syncthreads();
    const int cb = threadIdx.x & 7, r = threadIdx.x >> 3;   // r in [0,32)
#pragma unroll
    for (int half = 0; half < 2; half++) {
        int rr = r + half*32;
        const float* tp = &tile[rr][cb*8];
        u32 w0 = f2bf(tp[0]) | ((u32)f2bf(tp[1]) << 16);
        u32 w1 = f2bf(tp[2]) | ((u32)f2bf(tp[3]) << 16);
        u32 w2 = f2bf(tp[4]) | ((u32)f2bf(tp[5]) << 16);
        u32 w3 = f2bf(tp[6]) | ((u32)f2bf(tp[7]) << 16);
        *(uint4*)&xT[((size_t)b*NPIX + p0 + rr)*DIM + c0 + cb*8] = make_uint4(w0, w1, w2, w3);
    }
}

// ---------------- bilinear bias upsample 7x7 -> 56x56 (fp32 -> fp32) ----------------
__global__ __launch_bounds__(256) void upsample_bias(const float* __restrict__ src, float* __restrict__ dst) {
    int idx = blockIdx.x * 256 + threadIdx.x;          // < 12*49*3136
    int xo = idx % 56; int t = idx / 56;
    int yo = t % 56;   int ha = t / 56;                // h*49 + a
    float fy = yo * 0.125f - 0.4375f;
    float fx = xo * 0.125f - 0.4375f;
    float y0f = floorf(fy), x0f = floorf(fx);
    float wy = fy - y0f, wx = fx - x0f;
    int y0 = (int)y0f, x0 = (int)x0f;
    int y0c = max(y0, 0), y1c = min(y0 + 1, 6);
    int x0c = max(x0, 0), x1c = min(x0 + 1, 6);
    const float* sp = src + (size_t)ha * 49;
    float v00 = sp[y0c*7 + x0c], v01 = sp[y0c*7 + x1c];
    float v10 = sp[y1c*7 + x0c], v11 = sp[y1c*7 + x1c];
    dst[idx] = (1.f-wy)*((1.f-wx)*v00 + wx*v01) + wy*((1.f-wx)*v10 + wx*v11);
}

// ---------------- zero-init for stage1 partial accumulators ----------------
__global__ __launch_bounds__(256) void zero_init(float* __restrict__ p, int n) {
    int i = blockIdx.x * 256 + threadIdx.x;
    if (i < n) p[i] = 0.f;
}

// ---------------- shared MFMA fragment compute (tiles staged in As/Bs, XOR swizzle) ----------------
__device__ __forceinline__ void mfma_tile(const short* As, const short* Bs, f32x4 acc[4][4],
                                          int wm, int wn, int quad, int lr) {
#pragma unroll
    for (int ks = 0; ks < 2; ks++) {
        int g = ks*4 + quad;
        short8 af[4], bg[4];
#pragma unroll
        for (int im = 0; im < 4; im++) {
            int r = wm*64 + im*16 + lr;
            af[im] = *(const short8*)&As[r*64 + ((g ^ (r & 7)) << 3)];
        }
#pragma unroll
        for (int in_ = 0; in_ < 4; in_++) {
            int r = wn*64 + in_*16 + lr;
            bg[in_] = *(const short8*)&Bs[r*64 + ((g ^ (r & 7)) << 3)];
        }
#pragma unroll
        for (int im = 0; im < 4; im++)
#pragma unroll
            for (int in_ = 0; in_ < 4; in_++)
                acc[im][in_] = __builtin_amdgcn_mfma_f32_16x16x32_bf16(af[im], bg[in_], acc[im][in_], 0, 0, 0);
    }
}

// QKV GEMM: xT(bf16)[b][3136][384] @ qkvwT(bf16)[1152][384]^T -> per-head q/k/v bf16.
// 2-phase double-buffered global_load_lds staging; XOR swizzle realized by pre-swizzled
// global source column (LDS dest linear per lane): gsrc = (lane&7) ^ (lane>>3).
__global__ __launch_bounds__(256) void gemm_qkv(const u16* __restrict__ xT, const u16* __restrict__ Bw,
                                                const float* __restrict__ bias,
                                                u16* __restrict__ qb, u16* __restrict__ kb, u16* __restrict__ vb) {
    __shared__ __align__(16) short As[2][128*64];
    __shared__ __align__(16) short Bs[2][128*64];
    f32x4 acc[4][4] = {};
    const int l  = blockIdx.x + 9*(blockIdx.y + 25*blockIdx.z);   // hardware linear id (x fastest)
    const int k8 = l & 7, j = l >> 3;          // j in [0,900)
    const int c  = (j/9)*8 + k8;               // chunk = p + 25*b, [0,800)
    const int i9 = j - (j/9)*9;                // n-tile [0,9)
    const int n0 = i9 * 128;
    const int p0 = (c % 25) * 128;
    const int bb = c / 25;
    const int tid  = threadIdx.x;
    const int lane = tid & 63, wave = tid >> 6;
    const int wm = wave >> 1, wn = wave & 1;
    const int quad = lane >> 4, lr = lane & 15;
    const int rsub = lane >> 3;                // row within 8-row chunk
    const int gsrc = (lane & 7) ^ rsub;        // pre-swizzled source column group

    const u16* arow = xT + ((size_t)bb*NPIX + p0 + rsub)*DIM + gsrc*8;
    const u16* brow = Bw + ((size_t)(n0 + rsub))*DIM + gsrc*8;

#define QKV_STAGE(b2, kt)                                                       \
    {                                                                           \
        _Pragma("unroll")                                                       \
        for (int cc = 0; cc < 4; cc++) {                                        \
            int rowb = cc*32 + wave*8;                                          \
            glds16(arow + (size_t)rowb*DIM + (kt), &As[b2][rowb*64]);           \
            glds16(brow + (size_t)rowb*DIM + (kt), &Bs[b2][rowb*64]);           \
        }                                                                       \
    }

    QKV_STAGE(0, 0);
    __syncthreads();                           // vmcnt(0) drain: buf0 ready
    int buf = 0;
    for (int t = 0; t < 6; t++) {
        if (t < 5) QKV_STAGE(buf ^ 1, (t + 1)*64);   // next tile in flight during MFMA
        mfma_tile(As[buf], Bs[buf], acc, wm, wn, quad, lr);
        __syncthreads();                       // drain next-tile loads; guard WAR on buf
        buf ^= 1;
    }
#undef QKV_STAGE

    // --- epilogue: scatter into per-head q/k/v (bf16) ---
#pragma unroll
    for (int in_ = 0; in_ < 4; in_++) {
        int col = n0 + wn*64 + in_*16 + lr;           // < 1152
        int which = col / 384;
        int ch = col - which*384;
        int head = ch >> 5, d = ch & 31;
        float bcol = bias[col];
        u16* dstp = (which == 0) ? qb : ((which == 1) ? kb : vb);
#pragma unroll
        for (int im = 0; im < 4; im++) {
            int prow = p0 + wm*64 + im*16 + quad*4;
#pragma unroll
            for (int r = 0; r < 4; r++) {
                int pix = prow + r;
                if (pix < NPIX) {
                    float v = acc[im][in_][r] + bcol;
                    dstp[((size_t)(bb*HEADS + head)*NPIX + pix)*HD + d] = f2bf(v);
                }
            }
        }
    }
}

// proj GEMM: obuf(bf16)[100352][384] @ projwT(bf16)[384][384]^T + bias -> out = x * sigmoid(.) fp32 NCHW
__global__ __launch_bounds__(256) void gemm_proj(const u16* __restrict__ A, const u16* __restrict__ Bw,
                                                 const float* __restrict__ bias, const float* __restrict__ xin,
                                                 float* __restrict__ outp) {
    __shared__ __align__(16) short As[2][128*64];
    __shared__ __align__(16) short Bs[2][128*64];
    f32x4 acc[4][4] = {};
    const int l  = blockIdx.x + 3*blockIdx.y;  // [0,2352)
    const int k8 = l & 7, j = l >> 3;          // j in [0,294)
    const int c  = (j/3)*8 + k8;               // m-chunk [0,784)
    const int i3 = j - (j/3)*3;                // n-tile [0,3)
    const int n0 = i3*128, m0 = c*128;
    const int tid  = threadIdx.x;
    const int lane = tid & 63, wave = tid >> 6;
    const int wm = wave >> 1, wn = wave & 1;
    const int quad = lane >> 4, lr = lane & 15;
    const int rsub = lane >> 3;
    const int gsrc = (lane & 7) ^ rsub;

    const u16* arow = A  + ((size_t)(m0 + rsub))*DIM + gsrc*8;
    const u16* brow = Bw + ((size_t)(n0 + rsub))*DIM + gsrc*8;

#define PROJ_STAGE(b2, kt)                                                      \
    {                                                                           \
        _Pragma("unroll")                                                       \
        for (int cc = 0; cc < 4; cc++) {                                        \
            int rowb = cc*32 + wave*8;                                          \
            glds16(arow + (size_t)rowb*DIM + (kt), &As[b2][rowb*64]);           \
            glds16(brow + (size_t)rowb*DIM + (kt), &Bs[b2][rowb*64]);           \
        }                                                                       \
    }

    PROJ_STAGE(0, 0);
    __syncthreads();
    int buf = 0;
    for (int t = 0; t < 6; t++) {
        if (t < 5) PROJ_STAGE(buf ^ 1, (t + 1)*64);
        mfma_tile(As[buf], Bs[buf], acc, wm, wn, quad, lr);
        __syncthreads();
        buf ^= 1;
    }
#undef PROJ_STAGE

#pragma unroll
    for (int in_ = 0; in_ < 4; in_++) {
        int col = n0 + wn*64 + in_*16 + lr;           // < 384
        float bcol = bias[col];
#pragma unroll
        for (int im = 0; im < 4; im++) {
            int rowb = m0 + wm*64 + im*16 + quad*4;
#pragma unroll
            for (int r = 0; r < 4; r++) {
                int grow = rowb + r;
                int bb = grow / NPIX;
                int pix = grow - bb*NPIX;
                float o = acc[im][in_][r] + bcol;
                float sg = 1.f / (1.f + __expf(-o));
                size_t xi = ((size_t)bb*DIM + col)*NPIX + pix;
                outp[xi] = xin[xi] * sg;
            }
        }
    }
}

// ---------------- agent pooling: 8x8 mean of q(bf16) -> agent [b][H][49][32] fp32 ----------------
__global__ __launch_bounds__(256) void pool_q(const u16* __restrict__ qb, float* __restrict__ agent) {
    int gt = blockIdx.x * 256 + threadIdx.x;          // < 32*12*49*32
    int d = gt & 31;
    int t2 = gt >> 5;
    int a = t2 % 49;
    int bh = t2 / 49;
    int ay = a / 7, ax = a % 7;
    const u16* qp = qb + (size_t)bh*NPIX*HD + d;
    float s = 0.f;
#pragma unroll
    for (int dy = 0; dy < 8; dy++)
#pragma unroll
        for (int dx = 0; dx < 8; dx++)
            s += bf2f(qp[(size_t)((ay*8 + dy)*56 + ax*8 + dx)*HD]);
    agent[gt] = s * (1.f/64.f);
}

// ---------------- stage 1: pixel-chunked partial softmax + PV ----------------
#define S1_CHUNK  224
#define S1_NCHUNK 14          // 3136 / 224
#define S1_PSTR   228         // P_s row stride: 2-way-bank writes (free), rows 16B-aligned

__global__ __launch_bounds__(256) void stage1_part(const u16* __restrict__ kb, const u16* __restrict__ vb,
                                                   const float* __restrict__ agent, const float* __restrict__ pb1,
                                                   float* __restrict__ accv, float* __restrict__ accl) {
    __shared__ __align__(16) float ah_s[AGENTS*HD];        //  6272 B
    __shared__ __align__(16) float P_s[AGENTS*S1_PSTR];    // 44688 B, P transposed [a][pix]
    const int chunk = blockIdx.x;
    const int bh    = blockIdx.y;
    const int hh    = bh % HEADS;
    const int tid   = threadIdx.x;
    const int pix0  = chunk * S1_CHUNK;
    const float scale = 0.1767766952966369f;  // 32^-0.5

    for (int i = tid; i < AGENTS*HD; i += 256)
        ah_s[i] = agent[(size_t)bh*AGENTS*HD + i];
    __syncthreads();

    // phase A: one pixel per thread, 49 scores -> exp -> P_s[a][pix]
    if (tid < S1_CHUNK) {
        float kf[32];
        unpack_row32(kb + ((size_t)bh*NPIX + pix0 + tid)*HD, kf);
        const float* pbp = pb1 + (size_t)hh*AGENTS*NPIX + pix0 + tid;
        for (int a = 0; a < AGENTS; a++) {
            const float* ap = &ah_s[a*HD];                 // wave-uniform -> LDS broadcast
            float s0 = 0.f, s1 = 0.f, s2 = 0.f, s3 = 0.f;
#pragma unroll
            for (int d = 0; d < 32; d += 4) {
                s0 = fmaf(ap[d+0], kf[d+0], s0);
                s1 = fmaf(ap[d+1], kf[d+1], s1);
                s2 = fmaf(ap[d+2], kf[d+2], s2);
                s3 = fmaf(ap[d+3], kf[d+3], s3);
            }
            float s = ((s0+s1)+(s2+s3))*scale + pbp[(size_t)a*NPIX];
            P_s[a*S1_PSTR + tid] = __expf(s);
        }
    }
    __syncthreads();

    // partial denominators: l[a] = sum_pix P[a][pix]  (196 threads: a x 4 sub-stripes)
    if (tid < 196) {
        int a = tid >> 2, sub = tid & 3;
        const float* pp = &P_s[a*S1_PSTR + sub*56];
        float ls = 0.f;
        for (int k = 0; k < 56; k++) ls += pp[k];
        ls += __shfl_xor(ls, 1, 64);
        ls += __shfl_xor(ls, 2, 64);
        if (sub == 0) atomicAdd(&accl[(size_t)bh*AGENTS + a], ls);
    }

    // phase B: acc[a] += P[a][pix] * V[pix][d], thread (g,d) owns 7 groups of 4 pixels
    const int d = tid & 31, g = tid >> 5;                  // g: 0..7
    float acc[AGENTS];
#pragma unroll
    for (int a = 0; a < AGENTS; a++) acc[a] = 0.f;
    const u16* vp = vb + ((size_t)bh*NPIX + pix0)*HD + d;
    for (int p8 = 0; p8 < 7; p8++) {
        int pixl = p8*32 + g*4;
        float v0 = bf2f(vp[(size_t)(pixl+0)*HD]);
        float v1 = bf2f(vp[(size_t)(pixl+1)*HD]);
        float v2 = bf2f(vp[(size_t)(pixl+2)*HD]);
        float v3 = bf2f(vp[(size_t)(pixl+3)*HD]);
#pragma unroll
        for (int a = 0; a < AGENTS; a++) {
            f32x4 pq = *(const f32x4*)&P_s[a*S1_PSTR + pixl];   // wave-uniform addr -> broadcast
            acc[a] = fmaf(pq[0], v0, fmaf(pq[1], v1, fmaf(pq[2], v2, fmaf(pq[3], v3, acc[a]))));
        }
    }
    __syncthreads();   // all P_s reads done before aliasing it as reduction scratch

    // reduce 8 g-groups: pair-sum via shfl across half-wave, then 4-wave LDS reduce
#pragma unroll
    for (int a = 0; a < AGENTS; a++) acc[a] += __shfl_xor(acc[a], 32, 64);
    float* red = (float*)P_s;                              // [4][AGENTS][HD] = 25088 B, fits
    const int w = tid >> 6;
    if ((tid & 63) < 32) {
#pragma unroll
        for (int a = 0; a < AGENTS; a++) red[(w*AGENTS + a)*HD + d] = acc[a];
    }
    __syncthreads();
    for (int i = tid; i < AGENTS*HD; i += 256) {
        float s = red[i] + red[AGENTS*HD + i] + red[2*AGENTS*HD + i] + red[3*AGENTS*HD + i];
        atomicAdd(&accv[(size_t)bh*AGENTS*HD + i], s);
    }
}

__global__ __launch_bounds__(256) void stage1_final(const float* __restrict__ accv, const float* __restrict__ accl,
                                                    float* __restrict__ agentv) {
    int i = blockIdx.x * 256 + threadIdx.x;                // < 384*49*32
    agentv[i] = accv[i] / accl[i >> 5];
}

// ---------------- stage 2: o[pix,:] = softmax_a(scale*q.ah + ab1) @ agent_v -> obuf bf16 ----------------
__global__ __launch_bounds__(256) void stage2(const u16* __restrict__ qb, const float* __restrict__ agent,
                                              const float* __restrict__ agentv, const float* __restrict__ ab1,
                                              u16* __restrict__ obuf) {
    __shared__ float ah_s[AGENTS*32];
    __shared__ float av_s[AGENTS*32];
    const int b = blockIdx.z, hh = blockIdx.y, chunk = blockIdx.x;
    const int bh = b*HEADS + hh;
    for (int i = threadIdx.x; i < AGENTS*32; i += 256) {
        ah_s[i] = agent[(size_t)bh*AGENTS*HD + i];
        av_s[i] = agentv[(size_t)bh*AGENTS*HD + i];
    }
    __syncthreads();
    int pix = chunk*256 + threadIdx.x;
    if (pix >= NPIX) return;
    const float scale = 0.1767766952966369f;
    float qf[32];
    unpack_row32(qb + ((size_t)bh*NPIX + pix)*HD, qf);
    float oacc[32];
#pragma unroll
    for (int d = 0; d < 32; d++) oacc[d] = 0.f;
    float l = 0.f;
    const float* abp = ab1 + (size_t)hh*AGENTS*NPIX + pix;
    for (int a = 0; a < AGENTS; a++) {
        float s = 0.f;
#pragma unroll
        for (int d = 0; d < 32; d++) s = fmaf(qf[d], ah_s[a*32 + d], s);
        s = s * scale + abp[(size_t)a*NPIX];
        float p = __expf(s);
        l += p;
#pragma unroll
        for (int d = 0; d < 32; d++) oacc[d] = fmaf(p, av_s[a*32 + d], oacc[d]);
    }
    float inv = 1.f / l;
    u16* op = obuf + ((size_t)b*NPIX + pix)*DIM + hh*HD;
#pragma unroll
    for (int d2 = 0; d2 < 16; d2++) {
        u32 lo = f2bf(oacc[2*d2] * inv);
        u32 hi = f2bf(oacc[2*d2 + 1] * inv);
        ((u32*)op)[d2] = lo | (hi << 16);
    }
}

// ---------------- depthwise 3x3 conv on V (fp32 weights), added into obuf (bf16) ----------------
__global__ __launch_bounds__(256) void dwconv_add(const u16* __restrict__ vb, const float* __restrict__ dwcw,
                                                  const float* __restrict__ dwcb, u16* __restrict__ obuf) {
    const int chunk = blockIdx.x;       // 0..97 (32 pixels each)
    const int hh = blockIdx.y, b = blockIdx.z;
    const int dd = threadIdx.x & 31, pg = threadIdx.x >> 5;
    const int ch = hh*HD + dd;
    float wgt[9];
#pragma unroll
    for (int i = 0; i < 9; i++) wgt[i] = dwcw[ch*9 + i];
    float bbias = dwcb[ch];
    const u16* vp = vb + (size_t)(b*HEADS + hh)*NPIX*HD + dd;
#pragma unroll
    for (int i = 0; i < 4; i++) {
        int pix = chunk*32 + i*8 + pg;
        int y = pix / 56, x0 = pix - y*56;
        float s = bbias;
#pragma unroll
        for (int dy = 0; dy < 3; dy++) {
            int yy = y + dy - 1;
            if (yy < 0 || yy > 55) continue;
#pragma unroll
            for (int dx = 0; dx < 3; dx++) {
                int xx = x0 + dx - 1;
                if (xx < 0 || xx > 55) continue;
                s = fmaf(wgt[dy*3 + dx], bf2f(vp[(size_t)(yy*56 + xx)*HD]), s);
            }
        }
        size_t oi = ((size_t)b*NPIX + pix)*DIM + ch;
        obuf[oi] = f2bf(bf2f(obuf[oi]) + s);
    }
}

// ---------------- launch ----------------
extern "C" void kernel_launch(void* const* d_in, const int* in_sizes, int n_in,
                              void* d_out, int out_size, void* d_ws, size_t ws_size,
                              hipStream_t stream) {
    const float* x     = (const float*)d_in[0];
    const float* qkvw  = (const float*)d_in[1];
    const float* qkvb  = (const float*)d_in[2];
    const float* projw = (const float*)d_in[3];
    const float* projb = (const float*)d_in[4];
    const float* anb   = (const float*)d_in[5];
    const float* nab   = (const float*)d_in[6];
    const float* dwcw  = (const float*)d_in[7];
    const float* dwcb  = (const float*)d_in[8];
    float* out = (float*)d_out;

    // d_ws layout (221.6 MiB total)
    char* w = (char*)d_ws;
    const size_t SZ_BNC = (size_t)BATCH*NPIX*DIM*2;          // 77,070,336 B (bf16)
    u16* qb     = (u16*)w;  w += SZ_BNC;
    u16* kb     = (u16*)w;  w += SZ_BNC;                     // reused as obuf after stage1
    u16* vb     = (u16*)w;  w += SZ_BNC;
    u16* qkvwT  = (u16*)w;  w += (size_t)1152*384*2;
    u16* projwT = (u16*)w;  w += (size_t)384*384*2;
    u16* obuf   = kb;

    // stage-only buffers live in d_out (147 MB; all dead before gemm_proj rewrites d_out)
    char* o = (char*)d_out;
    float* pb1    = (float*)o; o += (size_t)HEADS*AGENTS*NPIX*4;      //  7.38 MB
    float* ab1    = (float*)o; o += (size_t)HEADS*AGENTS*NPIX*4;      //  7.38 MB
    float* agent  = (float*)o; o += (size_t)BATCH*HEADS*AGENTS*HD*4;  //  2.41 MB
    float* agentv = (float*)o; o += (size_t)BATCH*HEADS*AGENTS*HD*4;  //  2.41 MB
    float* accv   = (float*)o; o += (size_t)BATCH*HEADS*AGENTS*HD*4;  //  2.41 MB
    float* accl   = (float*)o; o += (size_t)BATCH*HEADS*AGENTS*4;     //  0.08 MB
    u16*   xT     = (u16*)o;   o += SZ_BNC;                           // 77.07 MB (total ~99 MB + tail slack)

    const int nacc = BATCH*HEADS*AGENTS*(HD + 1);            // accv + accl, contiguous

    convert_x    <<<dim3(49, 6, 32), 256, 0, stream>>>(x, xT);
    transpose_mat<<<dim3(18, 6),     256, 0, stream>>>(qkvw, qkvwT, 384, 1152);
    transpose_mat<<<dim3(6, 6),      256, 0, stream>>>(projw, projwT, 384, 384);
    upsample_bias<<<dim3(7203),      256, 0, stream>>>(anb, pb1);
    upsample_bias<<<dim3(7203),      256, 0, stream>>>(nab, ab1);
    zero_init    <<<dim3((nacc + 255)/256), 256, 0, stream>>>(accv, nacc);
    gemm_qkv     <<<dim3(9, 25, 32), 256, 0, stream>>>(xT, qkvwT, qkvb, qb, kb, vb);
    pool_q       <<<dim3(2352),      256, 0, stream>>>(qb, agent);
    stage1_part  <<<dim3(S1_NCHUNK, BATCH*HEADS), 256, 0, stream>>>(kb, vb, agent, pb1, accv, accl);
    stage1_final <<<dim3(2352),      256, 0, stream>>>(accv, accl, agentv);
    stage2       <<<dim3(13, 12, 32),256, 0, stream>>>(qb, agent, agentv, ab1, obuf);
    dwconv_add   <<<dim3(98, 12, 32),256, 0, stream>>>(vb, dwcw, dwcb, obuf);
    gemm_proj    <<<dim3(3, 784),    256, 0, stream>>>(obuf, projwT, projb, x, out);
}